// Round 2
// baseline (199.045 us; speedup 1.0000x reference)
//
#include <hip/hip_runtime.h>
#include <hip/hip_bf16.h>

typedef __attribute__((ext_vector_type(8))) short bf16x8;
typedef __attribute__((ext_vector_type(4))) float f32x4;
typedef __attribute__((ext_vector_type(2))) float f32x2;

#define BNSCL 0.9999950000375f   /* 1/sqrt(1+1e-5) */

// ---------------------------------------------------------------------------
// Kernel 0: rearrange weight_bank (128c,8m,64o) fp32 -> wbT bf16 [o][cm=c*8+m]
// ---------------------------------------------------------------------------
__global__ __launch_bounds__(256) void k_prep_wbt(const float* __restrict__ wb,
                                                  __hip_bfloat16* __restrict__ wbt)
{
    int idx = blockIdx.x * 256 + threadIdx.x;   // 0..65535
    int o = idx >> 10;
    int cm = idx & 1023;
    wbt[idx] = __float2bfloat16(wb[cm * 64 + o]);
}

// ---------------------------------------------------------------------------
// Kernel 1: per-point scores MLP + softmax. Weights staged in LDS (broadcast
// reads), 2 points per thread to amortize the ds_reads.
// LDS float offsets: w1 0, w2 112, w3 368, w4 624, b4 752,
//                    gs1 760, be1 776, gs2 792, be2 808, gs3 824, be3 840
// ---------------------------------------------------------------------------
__global__ __launch_bounds__(256) void k_scores(
    const float* __restrict__ xyz,
    const float* __restrict__ w1, const float* __restrict__ g1, const float* __restrict__ be1,
    const float* __restrict__ w2, const float* __restrict__ g2, const float* __restrict__ be2,
    const float* __restrict__ w3, const float* __restrict__ g3, const float* __restrict__ be3,
    const float* __restrict__ w4, const float* __restrict__ b4,
    float* __restrict__ scores)
{
    __shared__ float lw[856];
    const int tid = threadIdx.x;
    if (tid < 112) lw[tid] = w1[tid];
    lw[112 + tid] = w2[tid];
    lw[368 + tid] = w3[tid];
    if (tid < 128) lw[624 + tid] = w4[tid];
    if (tid < 8)   lw[752 + tid] = b4[tid];
    if (tid < 16) {
        lw[760 + tid] = g1[tid] * BNSCL;  lw[776 + tid] = be1[tid];
        lw[792 + tid] = g2[tid] * BNSCL;  lw[808 + tid] = be2[tid];
        lw[824 + tid] = g3[tid] * BNSCL;  lw[840 + tid] = be3[tid];
    }
    __syncthreads();

    float in7[2][7], h1[2][16], h2[2][16], s[2][8];

#pragma unroll
    for (int q = 0; q < 2; ++q) {
        int g = blockIdx.x * 512 + q * 256 + tid;   // 0..262143
        int b = g >> 15;
        int p = g & 32767;
        int pc = p & ~31;
        const float* xb = xyz + (size_t)b * 98304;  // (3, 32768)
        float cx = xb[pc], cy = xb[32768 + pc], cz = xb[65536 + pc];
        float dx = xb[p] - cx, dy = xb[32768 + p] - cy, dz = xb[65536 + p] - cz;
        in7[q][0] = cx; in7[q][1] = cy; in7[q][2] = cz;
        in7[q][3] = dx; in7[q][4] = dy; in7[q][5] = dz;
        in7[q][6] = sqrtf(dx * dx + dy * dy + dz * dz);
    }

#pragma unroll
    for (int o = 0; o < 16; ++o) {
        float a0 = 0.f, a1 = 0.f;
#pragma unroll
        for (int c = 0; c < 7; ++c) {
            float w = lw[o * 7 + c];
            a0 += w * in7[0][c]; a1 += w * in7[1][c];
        }
        float gs = lw[760 + o], bb = lw[776 + o];
        h1[0][o] = fmaxf(a0 * gs + bb, 0.f);
        h1[1][o] = fmaxf(a1 * gs + bb, 0.f);
    }
#pragma unroll
    for (int o = 0; o < 16; ++o) {
        float a0 = 0.f, a1 = 0.f;
#pragma unroll
        for (int c = 0; c < 16; ++c) {
            float w = lw[112 + o * 16 + c];
            a0 += w * h1[0][c]; a1 += w * h1[1][c];
        }
        float gs = lw[792 + o], bb = lw[808 + o];
        h2[0][o] = fmaxf(a0 * gs + bb, 0.f);
        h2[1][o] = fmaxf(a1 * gs + bb, 0.f);
    }
#pragma unroll
    for (int o = 0; o < 16; ++o) {
        float a0 = 0.f, a1 = 0.f;
#pragma unroll
        for (int c = 0; c < 16; ++c) {
            float w = lw[368 + o * 16 + c];
            a0 += w * h2[0][c]; a1 += w * h2[1][c];
        }
        float gs = lw[824 + o], bb = lw[840 + o];
        h1[0][o] = fmaxf(a0 * gs + bb, 0.f);     // reuse h1 = h3
        h1[1][o] = fmaxf(a1 * gs + bb, 0.f);
    }
#pragma unroll
    for (int o = 0; o < 8; ++o) {
        float bb = lw[752 + o];
        float a0 = bb, a1 = bb;
#pragma unroll
        for (int c = 0; c < 16; ++c) {
            float w = lw[624 + o * 16 + c];
            a0 += w * h1[0][c]; a1 += w * h1[1][c];
        }
        s[0][o] = a0; s[1][o] = a1;
    }

#pragma unroll
    for (int q = 0; q < 2; ++q) {
        int g = blockIdx.x * 512 + q * 256 + tid;
        float mx = s[q][0];
#pragma unroll
        for (int i = 1; i < 8; ++i) mx = fmaxf(mx, s[q][i]);
        float sum = 0.f;
#pragma unroll
        for (int i = 0; i < 8; ++i) { s[q][i] = __expf(s[q][i] - mx); sum += s[q][i]; }
        float inv = 1.f / sum;
        float4 lo = {s[q][0] * inv, s[q][1] * inv, s[q][2] * inv, s[q][3] * inv};
        float4 hi = {s[q][4] * inv, s[q][5] * inv, s[q][6] * inv, s[q][7] * inv};
        *(float4*)(scores + (size_t)g * 8) = lo;
        *(float4*)(scores + (size_t)g * 8 + 4) = hi;
    }
}

// ---------------------------------------------------------------------------
// Kernel 2: main einsum via MFMA.  D[o,p] = sum_cm wbT[o,cm] * (feat*s)[cm,p]
// Block = 512 thr (8 waves), 128 points. LDS = wbT quarter (64 o x 256 cm
// bf16, XOR-swizzled 16B chunks) = 32 KB -> 4 blocks/CU (32 waves).
// ---------------------------------------------------------------------------
__global__ __launch_bounds__(512, 8) void k_main(
    const float* __restrict__ feat,
    const float* __restrict__ scores,
    const __hip_bfloat16* __restrict__ wbt,
    const float* __restrict__ bn_g, const float* __restrict__ bn_b,
    float* __restrict__ out)
{
    __shared__ __align__(16) short lwb[64 * 256];   // 32 KB

    const int tid  = threadIdx.x;
    const int lane = tid & 63;
    const int wave = tid >> 6;          // 0..7
    const int col  = lane & 15;         // p within tile / o within A-row tile
    const int row4 = lane >> 4;         // 0..3 (k-quad)

    const int pblock = blockIdx.x * 128;
    const int b    = pblock >> 15;
    const int pl0  = pblock & 32767;
    const int pcol = pl0 + wave * 16 + col;   // point within batch b
    const int pcen = __builtin_amdgcn_readfirstlane(pcol & ~31); // wave-uniform
    const int gp   = pblock + wave * 16 + col;

    const float* fb = feat + (size_t)b * 2097152;   // (64, 32768)

    const float* sp = scores + (size_t)gp * 8;
    f32x2 s01 = *(const f32x2*)sp;
    f32x2 s23 = *(const f32x2*)(sp + 2);
    f32x2 s45 = *(const f32x2*)(sp + 4);
    f32x2 s67 = *(const f32x2*)(sp + 6);

    f32x4 acc[4];
#pragma unroll
    for (int i = 0; i < 4; ++i) { f32x4 z = {0.f, 0.f, 0.f, 0.f}; acc[i] = z; }

    const ushort* wsrc = (const ushort*)wbt;

#pragma unroll
    for (int phase = 0; phase < 4; ++phase) {
        // ---- stage wbT[:, phase*256 .. +256) into LDS, swizzled ----
#pragma unroll
        for (int it = 0; it < 4; ++it) {
            int chunk = it * 512 + tid;          // 0..2047
            int o = chunk >> 5, c8 = chunk & 31; // 32 chunks of 8 cm per o-row
            int4 v = *(const int4*)(wsrc + (o << 10) + (phase << 8) + (c8 << 3));
            *(int4*)&lwb[(o << 8) + (((c8 ^ o) & 31) << 3)] = v;
        }
        __syncthreads();

#pragma unroll 4
        for (int kk = 0; kk < 8; ++kk) {
            int cp = phase * 32 + kk * 4 + row4;         // c' in [0,128)
            float fv;
            if (phase < 2) {                              // diff half
                const float* fpc = fb + (size_t)cp * 32768;
                fv = fpc[pcol] - fpc[pcen];
            } else {                                      // raw half
                fv = fb[(size_t)(cp - 64) * 32768 + pcol];
            }

            f32x2 fvv = {fv, fv};
            f32x2 p0 = fvv * s01, p1 = fvv * s23, p2 = fvv * s45, p3 = fvv * s67;
            int4 bi;
            { __hip_bfloat162 q = __float22bfloat162_rn(make_float2(p0.x, p0.y)); __builtin_memcpy(&bi.x, &q, 4); }
            { __hip_bfloat162 q = __float22bfloat162_rn(make_float2(p1.x, p1.y)); __builtin_memcpy(&bi.y, &q, 4); }
            { __hip_bfloat162 q = __float22bfloat162_rn(make_float2(p2.x, p2.y)); __builtin_memcpy(&bi.z, &q, 4); }
            { __hip_bfloat162 q = __float22bfloat162_rn(make_float2(p3.x, p3.y)); __builtin_memcpy(&bi.w, &q, 4); }
            bf16x8 bv = __builtin_bit_cast(bf16x8, bi);

            int bcm = kk * 4 + row4;                      // 0..31
#pragma unroll
            for (int ot = 0; ot < 4; ++ot) {
                int o = ot * 16 + col;
                bf16x8 af = *(const bf16x8*)&lwb[(o << 8) + (((bcm ^ o) & 31) << 3)];
                acc[ot] = __builtin_amdgcn_mfma_f32_16x16x32_bf16(af, bv, acc[ot], 0, 0, 0);
            }
        }
        __syncthreads();
    }

    // ---------------- epilogue: BN + ReLU + store ------------------
#pragma unroll
    for (int ot = 0; ot < 4; ++ot) {
#pragma unroll
        for (int r = 0; r < 4; ++r) {
            int o = ot * 16 + row4 * 4 + r;          // D row = (lane>>4)*4 + reg
            float v = acc[ot][r];
            v = v * (bn_g[o] * BNSCL) + bn_b[o];
            v = fmaxf(v, 0.f);
            out[((size_t)(b * 64 + o) << 15) + pcol] = v;
        }
    }
}

// ---------------------------------------------------------------------------
extern "C" void kernel_launch(void* const* d_in, const int* in_sizes, int n_in,
                              void* d_out, int out_size, void* d_ws, size_t ws_size,
                              hipStream_t stream)
{
    const float* features = (const float*)d_in[0];
    const float* xyz      = (const float*)d_in[1];
    const float* w1  = (const float*)d_in[2];
    const float* g1  = (const float*)d_in[3];
    const float* be1 = (const float*)d_in[4];
    const float* w2  = (const float*)d_in[5];
    const float* g2  = (const float*)d_in[6];
    const float* be2 = (const float*)d_in[7];
    const float* w3  = (const float*)d_in[8];
    const float* g3  = (const float*)d_in[9];
    const float* be3 = (const float*)d_in[10];
    const float* w4  = (const float*)d_in[11];
    const float* b4  = (const float*)d_in[12];
    const float* wb  = (const float*)d_in[13];
    const float* bn_g = (const float*)d_in[14];
    const float* bn_b = (const float*)d_in[15];

    float* scores = (float*)d_ws;                                   // 8 MB
    __hip_bfloat16* wbt = (__hip_bfloat16*)((char*)d_ws + 8388608); // 128 KB

    k_prep_wbt<<<256, 256, 0, stream>>>(wb, wbt);
    k_scores<<<512, 256, 0, stream>>>(xyz, w1, g1, be1, w2, g2, be2,
                                      w3, g3, be3, w4, b4, scores);
    k_main<<<2048, 512, 0, stream>>>(features, scores, wbt, bn_g, bn_b,
                                     (float*)d_out);
}